// Round 8
// baseline (126.244 us; speedup 1.0000x reference)
//
#include <hip/hip_runtime.h>

#define NT 256
#define TW 32
#define TH 32
#define IH (TH + 10)   // 42 h-pass rows
#define HP 32          // LDS row stride in float4 units (swz handles banks; row term cancels mod 32)
#define IMW 512
#define IMH 512
#define NSLOT 64       // hashed accumulator slots
#define SLOTSTRIDE 16  // floats between slots (64 B -> no same-line bouncing)

// native 2-wide fp32 vector -> v_pk_fma_f32 / v_pk_mul_f32 on gfx950
typedef float f32x2 __attribute__((ext_vector_type(2)));

__device__ __forceinline__ float wave_reduce(float v) {
    #pragma unroll
    for (int off = 32; off > 0; off >>= 1)
        v += __shfl_down(v, off, 64);
    return v;
}

// LDS column swizzle (R2->R3: SQ_LDS_BANK_CONFLICT 4.13M -> 0).
// b128 LDS ops retire 8 lanes/cycle; every consecutive-8-lane group in both
// our patterns covers 8 distinct 4-bank groups after swz (row terms are
// multiples of 128B and cancel mod 32 banks) -> conflict-free at HP=32
// (verified R7: conflicts 0).
__device__ __forceinline__ int swz(int i) { return i ^ (i >> 3); }

// Gaussian 1-D weights for ws=11, sigma=1.5 (separable outer product == ref 2-D kernel)
#define G0 0.00102838f
#define G1 0.00759840f
#define G2 0.03600077f
#define G3 0.10936070f
#define G4 0.21300590f
#define G5 0.26601190f

// Horizontal pass. BORDER=false (interior blocks) has NO bounds logic at all.
// OOB lanes in the BORDER path are filled with -1.0, which (x+1)*0.5 maps to
// exactly 0 == reference zero-padding of the transformed image.
// Accumulator pairing (packed fp32): A0={p,a} A1={b,bb} A2={pp,aa} A3={pa,pb}
// LDS layout: h4a=(p,a,b,bb), h4b=(pp,aa,pa,pb).
template<bool BORDER>
__device__ __forceinline__ void h_pass(
    const float* __restrict__ Fp, const float* __restrict__ Ap,
    const float* __restrict__ Bp, int x0, int y0, int tid,
    float4* __restrict__ h4a, float4* __restrict__ h4b)
{
    const float g[11] = {G0, G1, G2, G3, G4, G5, G4, G3, G2, G1, G0};
    // IH*8 = 336 tasks > 256 threads: strided loop (1-2 iterations/thread)
    for (int idx = tid; idx < IH * 8; idx += NT) {
        const int r  = idx >> 3;
        const int cg = idx & 7;
        const int gy = y0 + r - 5;
        bool yok = true;
        if (BORDER) yok = (gy >= 0) && (gy < IMH);

        f32x2 accs[4][4];
        #pragma unroll
        for (int k = 0; k < 4; ++k)
            #pragma unroll
            for (int q = 0; q < 4; ++q) accs[k][q] = (f32x2){0.f, 0.f};

        const int xbase = x0 + 4 * cg - 8;
        #pragma unroll
        for (int w = 0; w < 5; ++w) {
            const int xc = xbase + 4 * w;
            float4 p4 = {-1.f, -1.f, -1.f, -1.f};
            float4 a4 = {-1.f, -1.f, -1.f, -1.f};
            float4 b4 = {-1.f, -1.f, -1.f, -1.f};
            bool ld = true;
            if (BORDER) ld = yok && (xc >= 0) && (xc < IMW);
            if (ld) {
                const size_t o = ((size_t)gy * IMW + xc) >> 2;  // float4 index
                p4 = ((const float4*)Fp)[o];
                a4 = ((const float4*)Ap)[o];
                b4 = ((const float4*)Bp)[o];
            }
            const float pe[4] = {p4.x, p4.y, p4.z, p4.w};
            const float ae[4] = {a4.x, a4.y, a4.z, a4.w};
            const float be[4] = {b4.x, b4.y, b4.z, b4.w};
            #pragma unroll
            for (int e = 0; e < 4; ++e) {
                const int i = 4 * w + e;
                if (i < 3 || i >= 17) continue;        // unused alignment slack
                const int t = i - 3;                   // window position 0..13
                const float p = fmaf(pe[e], 0.5f, 0.5f);
                const float a = fmaf(ae[e], 0.5f, 0.5f);
                const float b = fmaf(be[e], 0.5f, 0.5f);
                const f32x2 v_pa   = {p, a};
                const f32x2 v_ab   = {a, b};
                const f32x2 v_pp2  = {p, p};
                const f32x2 v_ppaa = v_pa * v_pa;      // {pp, aa}
                const f32x2 v_papb = v_pp2 * v_ab;     // {pa, pb}
                const f32x2 v_bbb  = {b, b * b};       // {b, bb}
                #pragma unroll
                for (int k = 0; k < 4; ++k) {
                    const int j = t - k;               // tap index
                    if (j < 0 || j > 10) continue;
                    const f32x2 w2 = {g[j], g[j]};
                    accs[k][0] += w2 * v_pa;           // v_pk_fma_f32
                    accs[k][1] += w2 * v_bbb;
                    accs[k][2] += w2 * v_ppaa;
                    accs[k][3] += w2 * v_papb;
                }
            }
        }
        #pragma unroll
        for (int k = 0; k < 4; ++k) {
            const int sc = swz(4 * cg + k);
            h4a[r * HP + sc] = make_float4(accs[k][0].x, accs[k][0].y,
                                           accs[k][1].x, accs[k][1].y);
            h4b[r * HP + sc] = make_float4(accs[k][2].x, accs[k][2].y,
                                           accs[k][3].x, accs[k][3].y);
        }
    }
}

__global__ __launch_bounds__(NT, 3) void ssim_main_kernel(
    const float* __restrict__ fused,
    const float* __restrict__ img_a,
    const float* __restrict__ img_b,
    float* __restrict__ acc_slots)
{
    // h-pass results: h4a=(p,a,b,bb), h4b=(pp,aa,pa,pb)
    // 2 * 42*32*16 B = 43008 B -> 3 blocks/CU; traded occupancy (R7: 5->6
    // bought nothing) for -19% h-pass work and -42% v-pass LDS reads.
    __shared__ float4 h4a[IH * HP];
    __shared__ float4 h4b[IH * HP];

    const float g[11] = {G0, G1, G2, G3, G4, G5, G4, G3, G2, G1, G0};

    const int tid = threadIdx.x;
    const int x0 = blockIdx.x * TW;
    const int y0 = blockIdx.y * TH;
    const size_t ioff = (size_t)blockIdx.z * IMW * IMH;
    const float* Fp = fused + ioff;
    const float* Ap = img_a + ioff;
    const float* Bp = img_b + ioff;

    const bool border = (blockIdx.x == 0) | (blockIdx.x == gridDim.x - 1) |
                        (blockIdx.y == 0) | (blockIdx.y == gridDim.y - 1);
    if (border) h_pass<true >(Fp, Ap, Bp, x0, y0, tid, h4a, h4b);
    else        h_pass<false>(Fp, Ap, Bp, x0, y0, tid, h4a, h4b);
    __syncthreads();

    // -------- vertical pass + SSIM, 4 consecutive rows per thread ----------
    // reads (4+10) rows * 2 b128 for 4 outputs = 7 b128/output (was 12).
    const float C1v = 1e-4f;
    const float C2v = 9e-4f;
    float lsum = 0.f;
    {
        const int c  = tid & 31;
        const int rg = tid >> 5;          // 0..7
        const int R0 = rg * 4;
        const int sc = swz(c);

        f32x2 m2[4][4];
        #pragma unroll
        for (int k = 0; k < 4; ++k)
            #pragma unroll
            for (int q = 0; q < 4; ++q) m2[k][q] = (f32x2){0.f, 0.f};

        #pragma unroll
        for (int j = 0; j < 14; ++j) {
            const float4 va = h4a[(R0 + j) * HP + sc];
            const float4 vb = h4b[(R0 + j) * HP + sc];
            const f32x2 va01 = {va.x, va.y};
            const f32x2 va23 = {va.z, va.w};
            const f32x2 vb01 = {vb.x, vb.y};
            const f32x2 vb23 = {vb.z, vb.w};
            #pragma unroll
            for (int k = 0; k < 4; ++k) {
                const int t = j - k;                 // tap index
                if (t < 0 || t > 10) continue;
                const f32x2 w2 = {g[t], g[t]};
                m2[k][0] += w2 * va01;               // v_pk_fma_f32
                m2[k][1] += w2 * va23;
                m2[k][2] += w2 * vb01;
                m2[k][3] += w2 * vb23;
            }
        }
        #pragma unroll
        for (int k = 0; k < 4; ++k) {
            const float mp  = m2[k][0].x, ma  = m2[k][0].y;
            const float mb  = m2[k][1].x, mbb = m2[k][1].y;
            const float mpp = m2[k][2].x, maa = m2[k][2].y;
            const float mpa = m2[k][3].x, mpb = m2[k][3].y;
            const float mp2 = mp * mp, ma2 = ma * ma, mb2 = mb * mb;
            const float s_p  = mpp - mp2;
            const float s_a  = maa - ma2;
            const float s_b  = mbb - mb2;
            const float s_pa = mpa - mp * ma;
            const float s_pb = mpb - mp * mb;
            const float na = (2.f * mp * ma + C1v) * (2.f * s_pa + C2v);
            const float da = (mp2 + ma2 + C1v) * (s_p + s_a + C2v);
            const float nb = (2.f * mp * mb + C1v) * (2.f * s_pb + C2v);
            const float db = (mp2 + mb2 + C1v) * (s_p + s_b + C2v);
            // v_rcp_f32 (~1 ulp) instead of divide; budget 1.98e-2 >> 1e-6
            lsum += na * __builtin_amdgcn_rcpf(da)
                  + nb * __builtin_amdgcn_rcpf(db);
        }
    }

    // -------- per-wave reduction -> one hashed-slot atomic per wave --------
    // NO fence, NO done-counter (R3: fence+counter serialized retirement).
    lsum = wave_reduce(lsum);
    if ((tid & 63) == 0) {
        const int lin = blockIdx.x + (int)gridDim.x * (blockIdx.y + (int)gridDim.y * blockIdx.z);
        const int slot = ((lin << 2) | (tid >> 6)) & (NSLOT - 1);
        atomicAdd(&acc_slots[slot * SLOTSTRIDE], lsum);
    }
}

__global__ void ssim_finalize_kernel(const float* __restrict__ acc_slots,
                                     float* __restrict__ out, float invTwoN) {
    float v = acc_slots[threadIdx.x * SLOTSTRIDE];   // 64 threads, one slot each
    v = wave_reduce(v);
    if (threadIdx.x == 0) out[0] = 1.f - v * invTwoN;
}

extern "C" void kernel_launch(void* const* d_in, const int* in_sizes, int n_in,
                              void* d_out, int out_size, void* d_ws, size_t ws_size,
                              hipStream_t stream) {
    const float* fused = (const float*)d_in[0];
    const float* img_a = (const float*)d_in[1];
    const float* img_b = (const float*)d_in[2];
    float* out = (float*)d_out;
    float* acc = (float*)d_ws;

    hipMemsetAsync(acc, 0, NSLOT * SLOTSTRIDE * sizeof(float), stream);

    dim3 grid(IMW / TW, IMH / TH, 16);
    ssim_main_kernel<<<grid, NT, 0, stream>>>(fused, img_a, img_b, acc);

    const float invTwoN = 1.f / (2.f * 16.f * (float)IMW * (float)IMH);
    ssim_finalize_kernel<<<1, 64, 0, stream>>>(acc, out, invTwoN);
}

// Round 9
// 118.851 us; speedup vs baseline: 1.0622x; 1.0622x over previous
//
#include <hip/hip_runtime.h>

#define NT 256
#define TW 32
#define TH 16
#define IH (TH + 10)   // 26 h-pass rows
#define HP 32          // LDS row stride in float4 units (swz handles banks; row term cancels mod 32)
#define IMW 512
#define IMH 512
#define NBLK ((IMW / TW) * (IMH / TH) * 16)   // 8192 partial slots

// native 2-wide fp32 vector -> v_pk_fma_f32 / v_pk_mul_f32 on gfx950
typedef float f32x2 __attribute__((ext_vector_type(2)));

__device__ __forceinline__ float wave_reduce(float v) {
    #pragma unroll
    for (int off = 32; off > 0; off >>= 1)
        v += __shfl_down(v, off, 64);
    return v;
}

// LDS column swizzle (R2->R3: SQ_LDS_BANK_CONFLICT 4.13M -> 0; R7 verified
// conflict-free at HP=32: row terms are multiples of 128B and cancel mod 32
// banks; every consecutive-8-lane group covers distinct bank groups).
__device__ __forceinline__ int swz(int i) { return i ^ (i >> 3); }

// Gaussian 1-D weights for ws=11, sigma=1.5 (separable outer product == ref 2-D kernel)
#define G0 0.00102838f
#define G1 0.00759840f
#define G2 0.03600077f
#define G3 0.10936070f
#define G4 0.21300590f
#define G5 0.26601190f

// Horizontal pass. BORDER=false (82% of blocks) has NO bounds logic at all.
// OOB lanes in the BORDER path are filled with -1.0, which (x+1)*0.5 maps to
// exactly 0 == reference zero-padding of the transformed image.
// Accumulator pairing (packed fp32): A0={p,a} A1={b,bb} A2={pp,aa} A3={pa,pb}
// LDS layout: h4a=(p,a,b,bb), h4b=(pp,aa,pa,pb).
template<bool BORDER>
__device__ __forceinline__ void h_pass(
    const float* __restrict__ Fp, const float* __restrict__ Ap,
    const float* __restrict__ Bp, int x0, int y0, int tid,
    float4* __restrict__ h4a, float4* __restrict__ h4b)
{
    const float g[11] = {G0, G1, G2, G3, G4, G5, G4, G3, G2, G1, G0};
    if (tid >= IH * 8) return;
    const int r  = tid >> 3;
    const int cg = tid & 7;
    const int gy = y0 + r - 5;
    bool yok = true;
    if (BORDER) yok = (gy >= 0) && (gy < IMH);

    f32x2 accs[4][4];
    #pragma unroll
    for (int k = 0; k < 4; ++k)
        #pragma unroll
        for (int q = 0; q < 4; ++q) accs[k][q] = (f32x2){0.f, 0.f};

    const int xbase = x0 + 4 * cg - 8;
    #pragma unroll
    for (int w = 0; w < 5; ++w) {
        const int xc = xbase + 4 * w;
        float4 p4 = {-1.f, -1.f, -1.f, -1.f};
        float4 a4 = {-1.f, -1.f, -1.f, -1.f};
        float4 b4 = {-1.f, -1.f, -1.f, -1.f};
        bool ld = true;
        if (BORDER) ld = yok && (xc >= 0) && (xc < IMW);
        if (ld) {
            const size_t o = ((size_t)gy * IMW + xc) >> 2;  // float4 index
            p4 = ((const float4*)Fp)[o];
            a4 = ((const float4*)Ap)[o];
            b4 = ((const float4*)Bp)[o];
        }
        const float pe[4] = {p4.x, p4.y, p4.z, p4.w};
        const float ae[4] = {a4.x, a4.y, a4.z, a4.w};
        const float be[4] = {b4.x, b4.y, b4.z, b4.w};
        #pragma unroll
        for (int e = 0; e < 4; ++e) {
            const int i = 4 * w + e;
            if (i < 3 || i >= 17) continue;        // unused alignment slack
            const int t = i - 3;                   // window position 0..13
            // transform only the 14 used elements
            const float p = fmaf(pe[e], 0.5f, 0.5f);
            const float a = fmaf(ae[e], 0.5f, 0.5f);
            const float b = fmaf(be[e], 0.5f, 0.5f);
            // packed products
            const f32x2 v_pa   = {p, a};
            const f32x2 v_ab   = {a, b};
            const f32x2 v_pp2  = {p, p};
            const f32x2 v_ppaa = v_pa * v_pa;      // {pp, aa} v_pk_mul_f32
            const f32x2 v_papb = v_pp2 * v_ab;     // {pa, pb} v_pk_mul_f32
            const f32x2 v_bbb  = {b, b * b};       // {b, bb}
            #pragma unroll
            for (int k = 0; k < 4; ++k) {
                const int j = t - k;               // tap index
                if (j < 0 || j > 10) continue;
                const f32x2 w2 = {g[j], g[j]};
                accs[k][0] += w2 * v_pa;           // v_pk_fma_f32
                accs[k][1] += w2 * v_bbb;
                accs[k][2] += w2 * v_ppaa;
                accs[k][3] += w2 * v_papb;
            }
        }
    }
    #pragma unroll
    for (int k = 0; k < 4; ++k) {
        const int sc = swz(4 * cg + k);
        h4a[r * HP + sc] = make_float4(accs[k][0].x, accs[k][0].y,
                                       accs[k][1].x, accs[k][1].y);
        h4b[r * HP + sc] = make_float4(accs[k][2].x, accs[k][2].y,
                                       accs[k][3].x, accs[k][3].y);
    }
}

__global__ __launch_bounds__(NT, 6) void ssim_main_kernel(
    const float* __restrict__ fused,
    const float* __restrict__ img_a,
    const float* __restrict__ img_b,
    float* __restrict__ slots)           // NBLK per-block partials (plain stores)
{
    // h-pass results: h4a=(p,a,b,bb), h4b=(pp,aa,pa,pb)
    // 26624 B + 16 B red -> 6 blocks/CU (R7 config: best measured, 47 us)
    __shared__ float4 h4a[IH * HP];
    __shared__ float4 h4b[IH * HP];
    __shared__ float red[NT / 64];

    const float g[11] = {G0, G1, G2, G3, G4, G5, G4, G3, G2, G1, G0};

    const int tid = threadIdx.x;
    const int x0 = blockIdx.x * TW;
    const int y0 = blockIdx.y * TH;
    const size_t ioff = (size_t)blockIdx.z * IMW * IMH;
    const float* Fp = fused + ioff;
    const float* Ap = img_a + ioff;
    const float* Bp = img_b + ioff;

    const bool border = (blockIdx.x == 0) | (blockIdx.x == gridDim.x - 1) |
                        (blockIdx.y == 0) | (blockIdx.y == gridDim.y - 1);
    if (border) h_pass<true >(Fp, Ap, Bp, x0, y0, tid, h4a, h4b);
    else        h_pass<false>(Fp, Ap, Bp, x0, y0, tid, h4a, h4b);
    __syncthreads();

    // ---------------- vertical pass + SSIM, 2 consecutive rows per thread ----
    const float C1v = 1e-4f;
    const float C2v = 9e-4f;
    float lsum = 0.f;
    {
        const int c  = tid & 31;
        const int rg = tid >> 5;          // 0..7
        const int R0 = rg * 2;
        const int sc = swz(c);

        f32x2 m2[2][4];
        #pragma unroll
        for (int k = 0; k < 2; ++k)
            #pragma unroll
            for (int q = 0; q < 4; ++q) m2[k][q] = (f32x2){0.f, 0.f};

        #pragma unroll
        for (int j = 0; j < 12; ++j) {
            const float4 va = h4a[(R0 + j) * HP + sc];
            const float4 vb = h4b[(R0 + j) * HP + sc];
            const f32x2 va01 = {va.x, va.y};
            const f32x2 va23 = {va.z, va.w};
            const f32x2 vb01 = {vb.x, vb.y};
            const f32x2 vb23 = {vb.z, vb.w};
            #pragma unroll
            for (int k = 0; k < 2; ++k) {
                const int t = j - k;                 // tap index
                if (t < 0 || t > 10) continue;
                const f32x2 w2 = {g[t], g[t]};
                m2[k][0] += w2 * va01;               // v_pk_fma_f32
                m2[k][1] += w2 * va23;
                m2[k][2] += w2 * vb01;
                m2[k][3] += w2 * vb23;
            }
        }
        #pragma unroll
        for (int k = 0; k < 2; ++k) {
            const float mp  = m2[k][0].x, ma  = m2[k][0].y;
            const float mb  = m2[k][1].x, mbb = m2[k][1].y;
            const float mpp = m2[k][2].x, maa = m2[k][2].y;
            const float mpa = m2[k][3].x, mpb = m2[k][3].y;
            const float mp2 = mp * mp, ma2 = ma * ma, mb2 = mb * mb;
            const float s_p  = mpp - mp2;
            const float s_a  = maa - ma2;
            const float s_b  = mbb - mb2;
            const float s_pa = mpa - mp * ma;
            const float s_pb = mpb - mp * mb;
            const float na = (2.f * mp * ma + C1v) * (2.f * s_pa + C2v);
            const float da = (mp2 + ma2 + C1v) * (s_p + s_a + C2v);
            const float nb = (2.f * mp * mb + C1v) * (2.f * s_pb + C2v);
            const float db = (mp2 + mb2 + C1v) * (s_p + s_b + C2v);
            // v_rcp_f32 (~1 ulp) instead of divide; budget 1.98e-2 >> 1e-6
            lsum += na * __builtin_amdgcn_rcpf(da)
                  + nb * __builtin_amdgcn_rcpf(db);
        }
    }

    // ------- block reduction -> ONE PLAIN STORE per block (no atomics, ------
    // no memset needed: stores overwrite the 0xAA-poisoned workspace).
    // NO fence, NO done-counter (R3: fence+counter serialized retirement).
    lsum = wave_reduce(lsum);
    if ((tid & 63) == 0) red[tid >> 6] = lsum;
    __syncthreads();
    if (tid == 0) {
        const int lin = blockIdx.x + (int)gridDim.x * (blockIdx.y + (int)gridDim.y * blockIdx.z);
        slots[lin] = red[0] + red[1] + red[2] + red[3];
    }
}

__global__ __launch_bounds__(NT) void ssim_finalize_kernel(
    const float* __restrict__ slots, float* __restrict__ out, float invTwoN)
{
    __shared__ float red[NT / 64];
    float s = 0.f;
    const float4* s4 = (const float4*)slots;
    for (int i = threadIdx.x; i < NBLK / 4; i += NT) {
        const float4 v = s4[i];
        s += (v.x + v.y) + (v.z + v.w);
    }
    s = wave_reduce(s);
    if ((threadIdx.x & 63) == 0) red[threadIdx.x >> 6] = s;
    __syncthreads();
    if (threadIdx.x == 0)
        out[0] = 1.f - (red[0] + red[1] + red[2] + red[3]) * invTwoN;
}

extern "C" void kernel_launch(void* const* d_in, const int* in_sizes, int n_in,
                              void* d_out, int out_size, void* d_ws, size_t ws_size,
                              hipStream_t stream) {
    const float* fused = (const float*)d_in[0];
    const float* img_a = (const float*)d_in[1];
    const float* img_b = (const float*)d_in[2];
    float* out = (float*)d_out;
    float* slots = (float*)d_ws;   // NBLK floats = 32 KB of scratch

    dim3 grid(IMW / TW, IMH / TH, 16);
    ssim_main_kernel<<<grid, NT, 0, stream>>>(fused, img_a, img_b, slots);

    const float invTwoN = 1.f / (2.f * 16.f * (float)IMW * (float)IMH);
    ssim_finalize_kernel<<<1, NT, 0, stream>>>(slots, out, invTwoN);
}

// Round 10
// 117.101 us; speedup vs baseline: 1.0781x; 1.0149x over previous
//
#include <hip/hip_runtime.h>

#define NT 256
#define TW 32
#define TH 16
#define IH (TH + 10)   // 26 h-pass rows
#define HP 32          // LDS row stride in float4 units (swz handles banks; row term cancels mod 32)
#define IMW 512
#define IMH 512
#define NBLK ((IMW / TW) * (IMH / TH) * 16)   // 8192 partial slots

// native 2-wide fp32 vector -> v_pk_fma_f32 / v_pk_mul_f32 on gfx950
typedef float f32x2 __attribute__((ext_vector_type(2)));

__device__ __forceinline__ float wave_reduce(float v) {
    #pragma unroll
    for (int off = 32; off > 0; off >>= 1)
        v += __shfl_down(v, off, 64);
    return v;
}

// LDS column swizzle (R2->R3: SQ_LDS_BANK_CONFLICT 4.13M -> 0; R7/R8 verified
// conflict-free at HP=32 for both the store and the 4-row read pattern).
__device__ __forceinline__ int swz(int i) { return i ^ (i >> 3); }

// Gaussian 1-D weights for ws=11, sigma=1.5 (separable outer product == ref 2-D kernel)
#define G0 0.00102838f
#define G1 0.00759840f
#define G2 0.03600077f
#define G3 0.10936070f
#define G4 0.21300590f
#define G5 0.26601190f

// Horizontal pass (R9-identical). BORDER=false (82% of blocks): no bounds
// logic. OOB lanes filled with -1.0 -> transform maps to exactly 0 ==
// reference zero-padding. LDS: h4a=(p,a,b,bb), h4b=(pp,aa,pa,pb).
template<bool BORDER>
__device__ __forceinline__ void h_pass(
    const float* __restrict__ Fp, const float* __restrict__ Ap,
    const float* __restrict__ Bp, int x0, int y0, int tid,
    float4* __restrict__ h4a, float4* __restrict__ h4b)
{
    const float g[11] = {G0, G1, G2, G3, G4, G5, G4, G3, G2, G1, G0};
    if (tid >= IH * 8) return;
    const int r  = tid >> 3;
    const int cg = tid & 7;
    const int gy = y0 + r - 5;
    bool yok = true;
    if (BORDER) yok = (gy >= 0) && (gy < IMH);

    f32x2 accs[4][4];
    #pragma unroll
    for (int k = 0; k < 4; ++k)
        #pragma unroll
        for (int q = 0; q < 4; ++q) accs[k][q] = (f32x2){0.f, 0.f};

    const int xbase = x0 + 4 * cg - 8;
    #pragma unroll
    for (int w = 0; w < 5; ++w) {
        const int xc = xbase + 4 * w;
        float4 p4 = {-1.f, -1.f, -1.f, -1.f};
        float4 a4 = {-1.f, -1.f, -1.f, -1.f};
        float4 b4 = {-1.f, -1.f, -1.f, -1.f};
        bool ld = true;
        if (BORDER) ld = yok && (xc >= 0) && (xc < IMW);
        if (ld) {
            const size_t o = ((size_t)gy * IMW + xc) >> 2;  // float4 index
            p4 = ((const float4*)Fp)[o];
            a4 = ((const float4*)Ap)[o];
            b4 = ((const float4*)Bp)[o];
        }
        const float pe[4] = {p4.x, p4.y, p4.z, p4.w};
        const float ae[4] = {a4.x, a4.y, a4.z, a4.w};
        const float be[4] = {b4.x, b4.y, b4.z, b4.w};
        #pragma unroll
        for (int e = 0; e < 4; ++e) {
            const int i = 4 * w + e;
            if (i < 3 || i >= 17) continue;        // unused alignment slack
            const int t = i - 3;                   // window position 0..13
            const float p = fmaf(pe[e], 0.5f, 0.5f);
            const float a = fmaf(ae[e], 0.5f, 0.5f);
            const float b = fmaf(be[e], 0.5f, 0.5f);
            const f32x2 v_pa   = {p, a};
            const f32x2 v_ab   = {a, b};
            const f32x2 v_pp2  = {p, p};
            const f32x2 v_ppaa = v_pa * v_pa;      // {pp, aa} v_pk_mul_f32
            const f32x2 v_papb = v_pp2 * v_ab;     // {pa, pb} v_pk_mul_f32
            const f32x2 v_bbb  = {b, b * b};       // {b, bb}
            #pragma unroll
            for (int k = 0; k < 4; ++k) {
                const int j = t - k;               // tap index
                if (j < 0 || j > 10) continue;
                const f32x2 w2 = {g[j], g[j]};
                accs[k][0] += w2 * v_pa;           // v_pk_fma_f32
                accs[k][1] += w2 * v_bbb;
                accs[k][2] += w2 * v_ppaa;
                accs[k][3] += w2 * v_papb;
            }
        }
    }
    #pragma unroll
    for (int k = 0; k < 4; ++k) {
        const int sc = swz(4 * cg + k);
        h4a[r * HP + sc] = make_float4(accs[k][0].x, accs[k][0].y,
                                       accs[k][1].x, accs[k][1].y);
        h4b[r * HP + sc] = make_float4(accs[k][2].x, accs[k][2].y,
                                       accs[k][3].x, accs[k][3].y);
    }
}

__global__ __launch_bounds__(NT, 6) void ssim_main_kernel(
    const float* __restrict__ fused,
    const float* __restrict__ img_a,
    const float* __restrict__ img_b,
    float* __restrict__ slots)           // NBLK per-block partials (plain stores)
{
    // h-pass results: h4a=(p,a,b,bb), h4b=(pp,aa,pa,pb); 26.6 KB -> 6 blocks/CU
    __shared__ float4 h4a[IH * HP];
    __shared__ float4 h4b[IH * HP];
    __shared__ float red[NT / 64];

    const float g[11] = {G0, G1, G2, G3, G4, G5, G4, G3, G2, G1, G0};

    const int tid = threadIdx.x;
    const int x0 = blockIdx.x * TW;
    const int y0 = blockIdx.y * TH;
    const size_t ioff = (size_t)blockIdx.z * IMW * IMH;
    const float* Fp = fused + ioff;
    const float* Ap = img_a + ioff;
    const float* Bp = img_b + ioff;

    const bool border = (blockIdx.x == 0) | (blockIdx.x == gridDim.x - 1) |
                        (blockIdx.y == 0) | (blockIdx.y == gridDim.y - 1);
    if (border) h_pass<true >(Fp, Ap, Bp, x0, y0, tid, h4a, h4b);
    else        h_pass<false>(Fp, Ap, Bp, x0, y0, tid, h4a, h4b);
    __syncthreads();

    // ---- vertical pass + SSIM: 128 threads x 4 consecutive rows each ------
    // 7 b128/output (was 12 at 2 rows/thread); waves 2,3 idle here (their
    // h-share is done; they carry 0 into the reduction). R8 verified this
    // body's correctness and conflict-free reads.
    const float C1v = 1e-4f;
    const float C2v = 9e-4f;
    float lsum = 0.f;
    if (tid < 128) {
        const int c  = tid & 31;
        const int rg = (tid >> 5) & 3;    // 0..3
        const int R0 = rg * 4;
        const int sc = swz(c);

        f32x2 m2[4][4];
        #pragma unroll
        for (int k = 0; k < 4; ++k)
            #pragma unroll
            for (int q = 0; q < 4; ++q) m2[k][q] = (f32x2){0.f, 0.f};

        #pragma unroll
        for (int j = 0; j < 14; ++j) {
            const float4 va = h4a[(R0 + j) * HP + sc];
            const float4 vb = h4b[(R0 + j) * HP + sc];
            const f32x2 va01 = {va.x, va.y};
            const f32x2 va23 = {va.z, va.w};
            const f32x2 vb01 = {vb.x, vb.y};
            const f32x2 vb23 = {vb.z, vb.w};
            #pragma unroll
            for (int k = 0; k < 4; ++k) {
                const int t = j - k;                 // tap index
                if (t < 0 || t > 10) continue;
                const f32x2 w2 = {g[t], g[t]};
                m2[k][0] += w2 * va01;               // v_pk_fma_f32
                m2[k][1] += w2 * va23;
                m2[k][2] += w2 * vb01;
                m2[k][3] += w2 * vb23;
            }
        }
        #pragma unroll
        for (int k = 0; k < 4; ++k) {
            const float mp  = m2[k][0].x;
            const float mpp = m2[k][2].x;
            // pk-paired epilogue over {img_a, img_b}: identical formulas
            const f32x2 mu2 = {m2[k][0].y, m2[k][1].x};   // {ma, mb}
            const f32x2 mq2 = {m2[k][2].y, m2[k][1].y};   // {maa, mbb}
            const f32x2 m12 = {m2[k][3].x, m2[k][3].y};   // {mpa, mpb}
            const float mp2 = mp * mp;
            const float s_p = mpp - mp2;
            const f32x2 mpv = {mp, mp};
            const f32x2 s2  = mq2 - mu2 * mu2;            // {s_a, s_b}
            const f32x2 s12 = m12 - mpv * mu2;            // {s_pa, s_pb}
            const f32x2 c1v2 = {C1v, C1v};
            const f32x2 c2v2 = {C2v, C2v};
            const f32x2 two  = {2.f, 2.f};
            const f32x2 spv  = {s_p, s_p};
            const f32x2 mp2v = {mp2, mp2};
            const f32x2 num = (two * mpv * mu2 + c1v2) * (two * s12 + c2v2);
            const f32x2 den = (mp2v + mu2 * mu2 + c1v2) * (spv + s2 + c2v2);
            // v_rcp_f32 (~1 ulp) instead of divide; budget 1.98e-2 >> 1e-6
            lsum += num.x * __builtin_amdgcn_rcpf(den.x)
                  + num.y * __builtin_amdgcn_rcpf(den.y);
        }
    }

    // ------- block reduction -> ONE PLAIN STORE per block (no atomics, ------
    // no memset: stores overwrite the 0xAA-poisoned workspace).
    // NO fence, NO done-counter (R3: fence+counter serialized retirement).
    lsum = wave_reduce(lsum);
    if ((tid & 63) == 0) red[tid >> 6] = lsum;
    __syncthreads();
    if (tid == 0) {
        const int lin = blockIdx.x + (int)gridDim.x * (blockIdx.y + (int)gridDim.y * blockIdx.z);
        slots[lin] = red[0] + red[1] + red[2] + red[3];
    }
}

__global__ __launch_bounds__(NT) void ssim_finalize_kernel(
    const float* __restrict__ slots, float* __restrict__ out, float invTwoN)
{
    __shared__ float red[NT / 64];
    float s = 0.f;
    const float4* s4 = (const float4*)slots;
    for (int i = threadIdx.x; i < NBLK / 4; i += NT) {
        const float4 v = s4[i];
        s += (v.x + v.y) + (v.z + v.w);
    }
    s = wave_reduce(s);
    if ((threadIdx.x & 63) == 0) red[threadIdx.x >> 6] = s;
    __syncthreads();
    if (threadIdx.x == 0)
        out[0] = 1.f - (red[0] + red[1] + red[2] + red[3]) * invTwoN;
}

extern "C" void kernel_launch(void* const* d_in, const int* in_sizes, int n_in,
                              void* d_out, int out_size, void* d_ws, size_t ws_size,
                              hipStream_t stream) {
    const float* fused = (const float*)d_in[0];
    const float* img_a = (const float*)d_in[1];
    const float* img_b = (const float*)d_in[2];
    float* out = (float*)d_out;
    float* slots = (float*)d_ws;   // NBLK floats = 32 KB of scratch

    dim3 grid(IMW / TW, IMH / TH, 16);
    ssim_main_kernel<<<grid, NT, 0, stream>>>(fused, img_a, img_b, slots);

    const float invTwoN = 1.f / (2.f * 16.f * (float)IMW * (float)IMH);
    ssim_finalize_kernel<<<1, NT, 0, stream>>>(slots, out, invTwoN);
}

// Round 11
// 115.043 us; speedup vs baseline: 1.0974x; 1.0179x over previous
//
#include <hip/hip_runtime.h>

#define NT 256
#define TW 32
#define TH 16
#define IH (TH + 10)   // 26 h-pass rows
#define HP 32          // LDS row stride in float4 units (swz handles banks; row term cancels mod 32)
#define IMW 512
#define IMH 512
#define NBLK ((IMW / TW) * (IMH / TH) * 16)   // 8192 partial slots

// native 2-wide fp32 vector -> v_pk_fma_f32 / v_pk_mul_f32 on gfx950
typedef float f32x2 __attribute__((ext_vector_type(2)));

__device__ __forceinline__ float wave_reduce(float v) {
    #pragma unroll
    for (int off = 32; off > 0; off >>= 1)
        v += __shfl_down(v, off, 64);
    return v;
}

// LDS column swizzle (R2->R3: SQ_LDS_BANK_CONFLICT 4.13M -> 0; R7/R9 verified
// conflict-free at HP=32: row terms are multiples of 128B and cancel mod 32
// banks; every consecutive-8-lane group covers distinct bank groups).
__device__ __forceinline__ int swz(int i) { return i ^ (i >> 3); }

// Gaussian 1-D weights for ws=11, sigma=1.5 (separable outer product == ref 2-D kernel)
#define G0 0.00102838f
#define G1 0.00759840f
#define G2 0.03600077f
#define G3 0.10936070f
#define G4 0.21300590f
#define G5 0.26601190f

// Horizontal pass over RAW values (transform folded into the epilogue):
// OOB raw fill = -1.0. Identities (exact, incl. borders, since pad -1 maps to
// transformed 0): mu_p=(Mf+1)/2, s_p=(Mff-Mf^2)/4, s_pa=(Mfa-Mf*Ma)/4, etc.
// This removes 3 fmaf x 14 elements per h-thread vs the transformed path.
// LDS: h4a=(f,a,b,bb), h4b=(ff,aa,fa,fb)  (raw moments)
template<bool BORDER>
__device__ __forceinline__ void h_pass(
    const float* __restrict__ Fp, const float* __restrict__ Ap,
    const float* __restrict__ Bp, int x0, int y0, int tid,
    float4* __restrict__ h4a, float4* __restrict__ h4b)
{
    const float g[11] = {G0, G1, G2, G3, G4, G5, G4, G3, G2, G1, G0};
    if (tid >= IH * 8) return;
    const int r  = tid >> 3;
    const int cg = tid & 7;
    const int gy = y0 + r - 5;
    bool yok = true;
    if (BORDER) yok = (gy >= 0) && (gy < IMH);

    f32x2 accs[4][4];
    #pragma unroll
    for (int k = 0; k < 4; ++k)
        #pragma unroll
        for (int q = 0; q < 4; ++q) accs[k][q] = (f32x2){0.f, 0.f};

    const int xbase = x0 + 4 * cg - 8;
    #pragma unroll
    for (int w = 0; w < 5; ++w) {
        const int xc = xbase + 4 * w;
        float4 p4 = {-1.f, -1.f, -1.f, -1.f};
        float4 a4 = {-1.f, -1.f, -1.f, -1.f};
        float4 b4 = {-1.f, -1.f, -1.f, -1.f};
        bool ld = true;
        if (BORDER) ld = yok && (xc >= 0) && (xc < IMW);
        if (ld) {
            const size_t o = ((size_t)gy * IMW + xc) >> 2;  // float4 index
            p4 = ((const float4*)Fp)[o];
            a4 = ((const float4*)Ap)[o];
            b4 = ((const float4*)Bp)[o];
        }
        const float pe[4] = {p4.x, p4.y, p4.z, p4.w};
        const float ae[4] = {a4.x, a4.y, a4.z, a4.w};
        const float be[4] = {b4.x, b4.y, b4.z, b4.w};
        #pragma unroll
        for (int e = 0; e < 4; ++e) {
            const int i = 4 * w + e;
            if (i < 3 || i >= 17) continue;        // unused alignment slack
            const int t = i - 3;                   // window position 0..13
            const float p = pe[e];                 // RAW (no transform)
            const float a = ae[e];
            const float b = be[e];
            const f32x2 v_pa   = {p, a};
            const f32x2 v_ab   = {a, b};
            const f32x2 v_pp2  = {p, p};
            const f32x2 v_ppaa = v_pa * v_pa;      // {ff, aa} v_pk_mul_f32
            const f32x2 v_papb = v_pp2 * v_ab;     // {fa, fb} v_pk_mul_f32
            const f32x2 v_bbb  = {b, b * b};       // {b, bb}
            #pragma unroll
            for (int k = 0; k < 4; ++k) {
                const int j = t - k;               // tap index
                if (j < 0 || j > 10) continue;
                const f32x2 w2 = {g[j], g[j]};
                accs[k][0] += w2 * v_pa;           // v_pk_fma_f32
                accs[k][1] += w2 * v_bbb;
                accs[k][2] += w2 * v_ppaa;
                accs[k][3] += w2 * v_papb;
            }
        }
    }
    #pragma unroll
    for (int k = 0; k < 4; ++k) {
        const int sc = swz(4 * cg + k);
        h4a[r * HP + sc] = make_float4(accs[k][0].x, accs[k][0].y,
                                       accs[k][1].x, accs[k][1].y);
        h4b[r * HP + sc] = make_float4(accs[k][2].x, accs[k][2].y,
                                       accs[k][3].x, accs[k][3].y);
    }
}

__global__ __launch_bounds__(NT, 6) void ssim_main_kernel(
    const float* __restrict__ fused,
    const float* __restrict__ img_a,
    const float* __restrict__ img_b,
    float* __restrict__ slots)           // NBLK per-block partials (plain stores)
{
    // raw h-moments: h4a=(f,a,b,bb), h4b=(ff,aa,fa,fb); 26.6 KB -> 6 blocks/CU
    __shared__ float4 h4a[IH * HP];
    __shared__ float4 h4b[IH * HP];
    __shared__ float red[NT / 64];

    const float g[11] = {G0, G1, G2, G3, G4, G5, G4, G3, G2, G1, G0};

    const int tid = threadIdx.x;
    const int x0 = blockIdx.x * TW;
    const int y0 = blockIdx.y * TH;
    const size_t ioff = (size_t)blockIdx.z * IMW * IMH;
    const float* Fp = fused + ioff;
    const float* Ap = img_a + ioff;
    const float* Bp = img_b + ioff;

    const bool border = (blockIdx.x == 0) | (blockIdx.x == gridDim.x - 1) |
                        (blockIdx.y == 0) | (blockIdx.y == gridDim.y - 1);
    if (border) h_pass<true >(Fp, Ap, Bp, x0, y0, tid, h4a, h4b);
    else        h_pass<false>(Fp, Ap, Bp, x0, y0, tid, h4a, h4b);
    __syncthreads();

    // ---------------- vertical pass + SSIM, 2 consecutive rows per thread ----
    // (R9 structure: best measured. 256 threads all active.)
    const float C1v = 1e-4f;
    const float C2v = 9e-4f;
    float lsum = 0.f;
    {
        const int c  = tid & 31;
        const int rg = tid >> 5;          // 0..7
        const int R0 = rg * 2;
        const int sc = swz(c);

        f32x2 m2[2][4];
        #pragma unroll
        for (int k = 0; k < 2; ++k)
            #pragma unroll
            for (int q = 0; q < 4; ++q) m2[k][q] = (f32x2){0.f, 0.f};

        #pragma unroll
        for (int j = 0; j < 12; ++j) {
            const float4 va = h4a[(R0 + j) * HP + sc];
            const float4 vb = h4b[(R0 + j) * HP + sc];
            const f32x2 va01 = {va.x, va.y};
            const f32x2 va23 = {va.z, va.w};
            const f32x2 vb01 = {vb.x, vb.y};
            const f32x2 vb23 = {vb.z, vb.w};
            #pragma unroll
            for (int k = 0; k < 2; ++k) {
                const int t = j - k;                 // tap index
                if (t < 0 || t > 10) continue;
                const f32x2 w2 = {g[t], g[t]};
                m2[k][0] += w2 * va01;               // v_pk_fma_f32
                m2[k][1] += w2 * va23;
                m2[k][2] += w2 * vb01;
                m2[k][3] += w2 * vb23;
            }
        }
        #pragma unroll
        for (int k = 0; k < 2; ++k) {
            // raw moments
            const float Mf  = m2[k][0].x, Ma  = m2[k][0].y;
            const float Mb  = m2[k][1].x, Mbb = m2[k][1].y;
            const float Mff = m2[k][2].x, Maa = m2[k][2].y;
            const float Mfa = m2[k][3].x, Mfb = m2[k][3].y;
            // transformed-domain reconstruction (exact; see h_pass comment):
            // s_p = (Mff - Mf^2)/4, s_pa = (Mfa - Mf*Ma)/4
            // 2*mu_p*mu_a = (Mf+1)(Ma+1)/2 ; mu_p^2+mu_a^2 = ((Mf+1)^2+(Ma+1)^2)/4
            const float Fo = Mf + 1.f;
            const float Ao = Ma + 1.f;
            const float Bo = Mb + 1.f;
            const float sp  = fmaf(-Mf, Mf, Mff) * 0.25f;
            const float sa  = fmaf(-Ma, Ma, Maa) * 0.25f;
            const float sb  = fmaf(-Mb, Mb, Mbb) * 0.25f;
            const float spa = fmaf(-Mf, Ma, Mfa) * 0.25f;
            const float spb = fmaf(-Mf, Mb, Mfb) * 0.25f;
            const float Fo2 = Fo * Fo;
            const float na = fmaf(0.5f * Fo, Ao, C1v) * fmaf(2.f, spa, C2v);
            const float da = fmaf(0.25f, fmaf(Ao, Ao, Fo2), C1v) * (sp + sa + C2v);
            const float nb = fmaf(0.5f * Fo, Bo, C1v) * fmaf(2.f, spb, C2v);
            const float db = fmaf(0.25f, fmaf(Bo, Bo, Fo2), C1v) * (sp + sb + C2v);
            // v_rcp_f32 (~1 ulp) instead of divide; budget 1.98e-2 >> 1e-6
            lsum += na * __builtin_amdgcn_rcpf(da)
                  + nb * __builtin_amdgcn_rcpf(db);
        }
    }

    // ------- block reduction -> ONE PLAIN STORE per block (no atomics, ------
    // no memset: stores overwrite the 0xAA-poisoned workspace).
    // NO fence, NO done-counter (R3: fence+counter serialized retirement).
    lsum = wave_reduce(lsum);
    if ((tid & 63) == 0) red[tid >> 6] = lsum;
    __syncthreads();
    if (tid == 0) {
        const int lin = blockIdx.x + (int)gridDim.x * (blockIdx.y + (int)gridDim.y * blockIdx.z);
        slots[lin] = red[0] + red[1] + red[2] + red[3];
    }
}

__global__ __launch_bounds__(NT) void ssim_finalize_kernel(
    const float* __restrict__ slots, float* __restrict__ out, float invTwoN)
{
    __shared__ float red[NT / 64];
    float s = 0.f;
    const float4* s4 = (const float4*)slots;
    for (int i = threadIdx.x; i < NBLK / 4; i += NT) {
        const float4 v = s4[i];
        s += (v.x + v.y) + (v.z + v.w);
    }
    s = wave_reduce(s);
    if ((threadIdx.x & 63) == 0) red[threadIdx.x >> 6] = s;
    __syncthreads();
    if (threadIdx.x == 0)
        out[0] = 1.f - (red[0] + red[1] + red[2] + red[3]) * invTwoN;
}

extern "C" void kernel_launch(void* const* d_in, const int* in_sizes, int n_in,
                              void* d_out, int out_size, void* d_ws, size_t ws_size,
                              hipStream_t stream) {
    const float* fused = (const float*)d_in[0];
    const float* img_a = (const float*)d_in[1];
    const float* img_b = (const float*)d_in[2];
    float* out = (float*)d_out;
    float* slots = (float*)d_ws;   // NBLK floats = 32 KB of scratch

    dim3 grid(IMW / TW, IMH / TH, 16);
    ssim_main_kernel<<<grid, NT, 0, stream>>>(fused, img_a, img_b, slots);

    const float invTwoN = 1.f / (2.f * 16.f * (float)IMW * (float)IMH);
    ssim_finalize_kernel<<<1, NT, 0, stream>>>(slots, out, invTwoN);
}